// Round 12
// baseline (555.977 us; speedup 1.0000x reference)
//
#include <hip/hip_runtime.h>
#include <math.h>

typedef _Float16 h2 __attribute__((ext_vector_type(2)));
typedef _Float16 half4_t __attribute__((ext_vector_type(4)));
typedef float f32x4 __attribute__((ext_vector_type(4)));

__device__ inline h2 uph(unsigned u) { return __builtin_bit_cast(h2, u); }
__device__ inline unsigned pkh(float a, float b) {
    return __builtin_bit_cast(unsigned, __builtin_amdgcn_cvt_pkrtz(a, b));
}
__device__ inline float sigf(float x) { return 1.f / (1.f + expf(-x)); }

// ============================================================================
// repackall: all 10 weight tensors -> f16 [slab][chunk][tap][co16][ci16-rot]
// in one launch. ci slot (ci>>2) rotated by (co>>2)&3 (LDS bank floor).
// ============================================================================
__global__ __launch_bounds__(256) void repackall(
    const float* __restrict__ s0, const float* __restrict__ s1,
    const float* __restrict__ s2, const float* __restrict__ s3,
    const float* __restrict__ s4, const float* __restrict__ s5,
    const float* __restrict__ s6, const float* __restrict__ s7,
    const float* __restrict__ s8, const float* __restrict__ s9,
    _Float16* __restrict__ dst)
{
    int t = blockIdx.x * 256 + threadIdx.x;
    if (t >= 179712) return;
    const int offs[11] = {0, 6912, 20736, 48384, 76032, 103680, 124416,
                          131328, 158976, 172800, 179712};
    const int ciwA[10] = {16, 16, 32, 30, 20, 48, 16, 20, 10, 10};
    const int coA[10]  = {16, 32, 20, 20, 32, 16, 16, 30, 30, 10};
    const int nchA[10] = {1, 1, 2, 2, 2, 3, 1, 2, 1, 1};
    int seg = 0;
    while (t >= offs[seg + 1]) ++seg;
    int lt = t - offs[seg];
    const float* src = seg == 0 ? s0 : seg == 1 ? s1 : seg == 2 ? s2 :
                       seg == 3 ? s3 : seg == 4 ? s4 : seg == 5 ? s5 :
                       seg == 6 ? s6 : seg == 7 ? s7 : seg == 8 ? s8 : s9;
    int CIw = ciwA[seg], CO = coA[seg], NCH = nchA[seg];
    int cip = lt & 15, co = (lt >> 4) & 15, r = lt >> 8;
    int tap = r % 27, rc = r / 27;
    int chunk = rc % NCH, slab = rc / NCH;
    int slot_l = ((cip >> 2) - (co >> 2)) & 3;
    int gci = chunk * 16 + slot_l * 4 + (cip & 3);
    int gco = slab * 16 + co;
    float v = 0.f;
    if (gci < CIw && gco < CO) v = src[((size_t)gco * CIw + gci) * 27 + tap];
    dst[t] = (_Float16)v;
}

// ============================================================================
// conv3m32: D=32 MFMA conv, M=512 (16-row band), CO=16, ch-last f16.
// Cell-based staging (32B/thread/cell), swizzled LDS, reg prefetch.
// FUSE: d1c 1x1 conv folded via 16-lane shfl_xor reduce (fp32 out).
// ============================================================================
template<int NCH, int UPP, int UP2, int S2, bool FUSE>
__global__ __launch_bounds__(256) void conv3m32(
    const _Float16* __restrict__ up, const _Float16* __restrict__ src,
    const _Float16* __restrict__ bwg, const float* __restrict__ bias,
    _Float16* __restrict__ out, const float* __restrict__ w1c,
    const float* __restrict__ b1c, float* __restrict__ out32)
{
    constexpr int ROWS = 18, COLS = 34;
    constexpr int CELLS = 3 * ROWS * COLS;   // 1836
    constexpr int ITERS = 8;

    __shared__ __align__(16) _Float16 win[CELLS * 16];  // 58752 B
    __shared__ __align__(16) _Float16 bw[6912];

    const int tid  = threadIdx.x;
    const int lane = tid & 63;
    const int wv   = tid >> 6;
    const int l16  = lane & 15;
    const int quad = lane >> 4;

    const int h0 = (blockIdx.x & 1) * 16;
    const int d  = (blockIdx.x >> 1) & 31;
    const int n  = blockIdx.x >> 6;

    // hoisted per-cell staging state
    unsigned baseS[ITERS], baseU[ITERS], pk[ITERS];
    bool vld[ITERS];
#pragma unroll
    for (int it = 0; it < ITERS; ++it) {
        int t = tid + it * 256;
        vld[it] = false; baseS[it] = 0; baseU[it] = 0; pk[it] = 0;
        if (t < CELLS) {
            int cc = t % COLS, rr = t / COLS;
            int hh = rr % ROWS, dp = rr / ROWS;
            int zd = d - 1 + dp, zh = h0 + hh - 1, zw = cc - 1;
            vld[it] = (unsigned)zd < 32u && (unsigned)zh < 32u && (unsigned)zw < 32u;
            pk[it] = (unsigned)(t * 16) | ((unsigned)((cc >> 2) & 3) << 28);
            if (vld[it]) {
                baseS[it] = (unsigned)((((n * 32 + zd) * 32 + zh) * 32 + zw) * S2);
                if (UPP > 0)
                    baseU[it] = (unsigned)((((n * 16 + (zd >> 1)) * 16 + (zh >> 1)) * 16
                                            + (zw >> 1)) * UP2);
            }
        }
    }

    f32x4 acc[8];
    {
        float b0 = bias[l16];
#pragma unroll
        for (int i = 0; i < 8; ++i) acc[i] = f32x4{b0, b0, b0, b0};
    }
    const int brot = ((quad + (l16 >> 2)) & 3) << 2;

    uint4 preA0[ITERS], preA1[ITERS], preB[4];

    auto loadA = [&](int cib) {
        const int cb = cib * 16;
        const bool isup = (UPP > 0) && (cb < UPP);
#pragma unroll
        for (int it = 0; it < ITERS; ++it) {
            uint4 v0 = uint4{0u, 0u, 0u, 0u}, v1 = v0;
            int t = tid + it * 256;
            if (t < CELLS && vld[it]) {
                const _Float16* p = isup ? (up + baseU[it] + cb)
                                         : (src + baseS[it] + (cb - UPP));
                v0 = *(const uint4*)p;
                v1 = *(const uint4*)(p + 8);
            }
            preA0[it] = v0; preA1[it] = v1;
        }
    };
    auto loadB = [&](int cib) {
        const uint4* bsrc = (const uint4*)(bwg + (size_t)cib * 6912);
#pragma unroll
        for (int it = 0; it < 4; ++it) {
            int t = tid + it * 256;
            preB[it] = (t < 864) ? bsrc[t] : uint4{0u, 0u, 0u, 0u};
        }
    };

    loadA(0);
    loadB(0);

#pragma unroll
    for (int cib = 0; cib < NCH; ++cib) {
        if (cib) __syncthreads();
#pragma unroll
        for (int it = 0; it < 4; ++it) {
            int t = tid + it * 256;
            if (t < 864) ((uint4*)bw)[t] = preB[it];
        }
#pragma unroll
        for (int it = 0; it < ITERS; ++it) {
            int t = tid + it * 256;
            if (t < CELLS) {
                int cell = pk[it] & 0x0FFFFFFF;
                int rot  = pk[it] >> 28;
                *(uint2*)&win[cell + (((rot + 0) & 3) << 2)] = make_uint2(preA0[it].x, preA0[it].y);
                *(uint2*)&win[cell + (((rot + 1) & 3) << 2)] = make_uint2(preA0[it].z, preA0[it].w);
                *(uint2*)&win[cell + (((rot + 2) & 3) << 2)] = make_uint2(preA1[it].x, preA1[it].y);
                *(uint2*)&win[cell + (((rot + 3) & 3) << 2)] = make_uint2(preA1[it].z, preA1[it].w);
            }
        }
        if (cib + 1 < NCH) { loadA(cib + 1); loadB(cib + 1); }
        __syncthreads();

#pragma unroll
        for (int kd = 0; kd < 3; ++kd) {
#pragma unroll
            for (int kw = 0; kw < 3; ++kw) {
                half4_t bf[3];
#pragma unroll
                for (int kh = 0; kh < 3; ++kh)
                    bf[kh] = *(const half4_t*)&bw[((kd * 3 + kh) * 3 + kw) * 256 + l16 * 16 + brot];
                half4_t af[2][6];
#pragma unroll
                for (int p = 0; p < 2; ++p) {
                    const int ww = p * 16 + l16 + kw;
                    const int arot = ((quad + (ww >> 2)) & 3) << 2;
#pragma unroll
                    for (int rr = 0; rr < 6; ++rr) {
                        const int row = kd * ROWS + wv * 4 + rr;
                        af[p][rr] = *(const half4_t*)&win[(row * COLS + ww) * 16 + arot];
                    }
                }
#pragma unroll
                for (int kh = 0; kh < 3; ++kh)
#pragma unroll
                    for (int j = 0; j < 4; ++j)
#pragma unroll
                        for (int p = 0; p < 2; ++p)
                            acc[j * 2 + p] = __builtin_amdgcn_mfma_f32_16x16x16f16(
                                af[p][j + kh], bf[kh], acc[j * 2 + p], 0, 0, 0);
            }
        }
    }

    // epilogue: C layout col=l16=co, row=quad*4+r
    if (FUSE) {
        const float wc = w1c[l16];
        const float bb = b1c[0];
#pragma unroll
        for (int i = 0; i < 8; ++i) {
            const int h = h0 + wv * 4 + (i >> 1);
            const int wb0 = (i & 1) * 16;
#pragma unroll
            for (int r = 0; r < 4; ++r) {
                float v = fmaxf(acc[i][r], 0.f) * wc;
                v += __shfl_xor(v, 1);
                v += __shfl_xor(v, 2);
                v += __shfl_xor(v, 4);
                v += __shfl_xor(v, 8);
                if (l16 == 0) {
                    const int w = wb0 + quad * 4 + r;
                    out32[(((size_t)n * 32 + d) * 32 + h) * 32 + w] = v + bb;
                }
            }
        }
    } else {
#pragma unroll
        for (int i = 0; i < 8; ++i) {
            const int h = h0 + wv * 4 + (i >> 1);
            const int wb0 = (i & 1) * 16;
#pragma unroll
            for (int r = 0; r < 4; ++r) {
                const int w = wb0 + quad * 4 + r;
                size_t sp = (((size_t)n * 32 + d) * 32 + h) * 32 + w;
                out[sp * 16 + l16] = (_Float16)fmaxf(acc[i][r], 0.f);
            }
        }
    }
}

// ============================================================================
// conv3m16: D=16 MFMA conv, M=256 (full plane), NSLAB co-slabs per block.
// A-fragments shared across slabs (halves A LDS traffic vs slab-per-block).
// ============================================================================
template<int NCH, int NSLAB, int S2, int CO>
__global__ __launch_bounds__(256) void conv3m16(
    const _Float16* __restrict__ src, const _Float16* __restrict__ bwg,
    const float* __restrict__ bias, _Float16* __restrict__ out)
{
    constexpr int ROWS = 18, COLS = 18;
    constexpr int CELLS = 3 * ROWS * COLS;   // 972
    constexpr int ITERS = 4;

    __shared__ __align__(16) _Float16 win[CELLS * 16];
    __shared__ __align__(16) _Float16 bw[NSLAB * 6912];

    const int tid  = threadIdx.x;
    const int lane = tid & 63;
    const int wv   = tid >> 6;
    const int l16  = lane & 15;
    const int quad = lane >> 4;

    const int d = blockIdx.x & 15;
    const int n = blockIdx.x >> 4;

    unsigned baseS[ITERS], pk[ITERS];
    bool vld[ITERS];
#pragma unroll
    for (int it = 0; it < ITERS; ++it) {
        int t = tid + it * 256;
        vld[it] = false; baseS[it] = 0; pk[it] = 0;
        if (t < CELLS) {
            int cc = t % COLS, rr = t / COLS;
            int hh = rr % ROWS, dp = rr / ROWS;
            int zd = d - 1 + dp, zh = hh - 1, zw = cc - 1;
            vld[it] = (unsigned)zd < 16u && (unsigned)zh < 16u && (unsigned)zw < 16u;
            pk[it] = (unsigned)(t * 16) | ((unsigned)((cc >> 2) & 3) << 28);
            if (vld[it])
                baseS[it] = (unsigned)((((n * 16 + zd) * 16 + zh) * 16 + zw) * S2);
        }
    }

    f32x4 acc[NSLAB][4];
#pragma unroll
    for (int s = 0; s < NSLAB; ++s) {
        int cg = s * 16 + l16;
        float b0 = (cg < CO) ? bias[cg] : 0.f;
#pragma unroll
        for (int i = 0; i < 4; ++i) acc[s][i] = f32x4{b0, b0, b0, b0};
    }
    const int brot = ((quad + (l16 >> 2)) & 3) << 2;

    uint4 preA0[ITERS], preA1[ITERS], preB[NSLAB][4];

    auto loadA = [&](int cib) {
        const int cb = cib * 16;
#pragma unroll
        for (int it = 0; it < ITERS; ++it) {
            uint4 v0 = uint4{0u, 0u, 0u, 0u}, v1 = v0;
            int t = tid + it * 256;
            if (t < CELLS && vld[it]) {
                const _Float16* p = src + baseS[it] + cb;
                v0 = *(const uint4*)p;
                v1 = *(const uint4*)(p + 8);
            }
            preA0[it] = v0; preA1[it] = v1;
        }
    };
    auto loadB = [&](int cib) {
#pragma unroll
        for (int s = 0; s < NSLAB; ++s) {
            const uint4* bsrc = (const uint4*)(bwg + (size_t)(s * NCH + cib) * 6912);
#pragma unroll
            for (int it = 0; it < 4; ++it) {
                int t = tid + it * 256;
                preB[s][it] = (t < 864) ? bsrc[t] : uint4{0u, 0u, 0u, 0u};
            }
        }
    };

    loadA(0);
    loadB(0);

#pragma unroll
    for (int cib = 0; cib < NCH; ++cib) {
        if (cib) __syncthreads();
#pragma unroll
        for (int s = 0; s < NSLAB; ++s)
#pragma unroll
            for (int it = 0; it < 4; ++it) {
                int t = tid + it * 256;
                if (t < 864) ((uint4*)(bw + s * 6912))[t] = preB[s][it];
            }
#pragma unroll
        for (int it = 0; it < ITERS; ++it) {
            int t = tid + it * 256;
            if (t < CELLS) {
                int cell = pk[it] & 0x0FFFFFFF;
                int rot  = pk[it] >> 28;
                *(uint2*)&win[cell + (((rot + 0) & 3) << 2)] = make_uint2(preA0[it].x, preA0[it].y);
                *(uint2*)&win[cell + (((rot + 1) & 3) << 2)] = make_uint2(preA0[it].z, preA0[it].w);
                *(uint2*)&win[cell + (((rot + 2) & 3) << 2)] = make_uint2(preA1[it].x, preA1[it].y);
                *(uint2*)&win[cell + (((rot + 3) & 3) << 2)] = make_uint2(preA1[it].z, preA1[it].w);
            }
        }
        if (cib + 1 < NCH) { loadA(cib + 1); loadB(cib + 1); }
        __syncthreads();

#pragma unroll
        for (int kd = 0; kd < 3; ++kd) {
#pragma unroll
            for (int kw = 0; kw < 3; ++kw) {
                half4_t af[6];
                const int ww = l16 + kw;
                const int arot = ((quad + (ww >> 2)) & 3) << 2;
#pragma unroll
                for (int rr = 0; rr < 6; ++rr) {
                    const int row = kd * ROWS + wv * 4 + rr;
                    af[rr] = *(const half4_t*)&win[(row * COLS + ww) * 16 + arot];
                }
#pragma unroll
                for (int kh = 0; kh < 3; ++kh) {
                    const int tap = (kd * 3 + kh) * 3 + kw;
#pragma unroll
                    for (int s = 0; s < NSLAB; ++s) {
                        half4_t bf = *(const half4_t*)&bw[s * 6912 + tap * 256 + l16 * 16 + brot];
#pragma unroll
                        for (int i = 0; i < 4; ++i)
                            acc[s][i] = __builtin_amdgcn_mfma_f32_16x16x16f16(
                                af[i + kh], bf, acc[s][i], 0, 0, 0);
                    }
                }
            }
        }
    }

#pragma unroll
    for (int s = 0; s < NSLAB; ++s) {
        int cg = s * 16 + l16;
        if (cg < CO) {
#pragma unroll
            for (int i = 0; i < 4; ++i) {
                const int h = wv * 4 + i;
#pragma unroll
                for (int r = 0; r < 4; ++r) {
                    const int w = quad * 4 + r;
                    size_t sp = (((size_t)n * 16 + d) * 16 + h) * 16 + w;
                    out[sp * 32 + cg] = (_Float16)fmaxf(acc[s][i][r], 0.f);
                }
            }
        }
    }
}

// e1a: 1 fp32 input channel -> 16 co, D=32, channels-last out (stride 16)
__global__ __launch_bounds__(256) void conv3e1a(
    const float* __restrict__ src, const float* __restrict__ wgt,
    const float* __restrict__ bias, _Float16* __restrict__ out)
{
    __shared__ float sw[27 * 16];
    const int tid = threadIdx.x;
    const int wq = tid % 8;
    const int h  = (tid / 8) % 32;
    const int w0 = wq * 4;
    const int n  = blockIdx.x / 32;
    const int d  = blockIdx.x % 32;

    for (int t = tid; t < 27 * 16; t += 256) {
        int co = t % 16, tap = t / 16;
        sw[t] = wgt[(size_t)co * 27 + tap];
    }
    __syncthreads();

    float acc[16][4];
#pragma unroll
    for (int co = 0; co < 16; ++co) {
        float b0 = bias[co];
        acc[co][0] = b0; acc[co][1] = b0; acc[co][2] = b0; acc[co][3] = b0;
    }

#pragma unroll
    for (int kd = 0; kd < 3; ++kd) {
        int zd = d + kd - 1;
        if ((unsigned)zd >= 32u) continue;
#pragma unroll
        for (int kh = 0; kh < 3; ++kh) {
            int zh = h + kh - 1;
            if ((unsigned)zh >= 32u) continue;
            const float* p = src + ((size_t)n * 32 + zd) * 1024 + zh * 32;
            float v[6];
#pragma unroll
            for (int j = 0; j < 6; ++j) {
                int zw = w0 - 1 + j;
                v[j] = ((unsigned)zw < 32u) ? p[zw] : 0.f;
            }
            const float* swp = &sw[(kd * 9 + kh * 3) * 16];
#pragma unroll
            for (int kw = 0; kw < 3; ++kw)
#pragma unroll
                for (int co = 0; co < 16; ++co)
#pragma unroll
                    for (int j = 0; j < 4; ++j)
                        acc[co][j] = fmaf(v[kw + j], swp[kw * 16 + co], acc[co][j]);
        }
    }

#pragma unroll
    for (int j = 0; j < 4; ++j) {
        unsigned u[8];
#pragma unroll
        for (int cp = 0; cp < 8; ++cp)
            u[cp] = pkh(fmaxf(acc[2 * cp][j], 0.f), fmaxf(acc[2 * cp + 1][j], 0.f));
        _Float16* base = out + ((((size_t)n * 32 + d) * 32 + h) * 32 + (w0 + j)) * 16;
        *(uint4*)base       = make_uint4(u[0], u[1], u[2], u[3]);
        *(uint4*)(base + 8) = make_uint4(u[4], u[5], u[6], u[7]);
    }
}

// 2x2x2 maxpool, channels-last stride-16 (x0 32^3 -> xp 16^3)
__global__ __launch_bounds__(256) void maxpool16(
    const unsigned* __restrict__ in, unsigned* __restrict__ out, int total)
{
    int t = blockIdx.x * 256 + threadIdx.x;
    if (t >= total) return;
    int cp = t & 7, w = (t >> 3) & 15, h = (t >> 7) & 15, d = (t >> 11) & 15, n = t >> 15;
    float m0 = -1e30f, m1 = -1e30f;
#pragma unroll
    for (int a = 0; a < 2; ++a)
#pragma unroll
        for (int b = 0; b < 2; ++b)
#pragma unroll
            for (int c = 0; c < 2; ++c) {
                size_t sp = (((size_t)n * 32 + 2 * d + a) * 32 + 2 * h + b) * 32 + 2 * w + c;
                h2 x = uph(in[sp * 8 + cp]);
                m0 = fmaxf(m0, (float)x.x);
                m1 = fmaxf(m1, (float)x.y);
            }
    out[(((size_t)(n * 16 + d) * 16 + h) * 16 + w) * 8 + cp] = pkh(m0, m1);
}

// 2x2x2 maxpool: x1 (ch-last stride 32 @16^3) -> xp2 ch-last [31][512][32]
__global__ __launch_bounds__(256) void poolx1(
    const unsigned* __restrict__ x1u, unsigned* __restrict__ out, int total)
{
    int t = blockIdx.x * 256 + threadIdx.x;
    if (t >= total) return;
    int cp = t & 15, s = (t >> 4) & 511, n = t >> 13;
    int w = s & 7, h = (s >> 3) & 7, d = s >> 6;
    unsigned o = 0u;
    if (cp < 10) {
        float m0 = -1e30f, m1 = -1e30f;
#pragma unroll
        for (int a = 0; a < 2; ++a)
#pragma unroll
            for (int b = 0; b < 2; ++b)
#pragma unroll
                for (int c = 0; c < 2; ++c) {
                    size_t sp = (((size_t)n * 16 + 2 * d + a) * 16 + 2 * h + b) * 16 + 2 * w + c;
                    h2 x = uph(x1u[sp * 16 + cp]);
                    m0 = fmaxf(m0, (float)x.x);
                    m1 = fmaxf(m1, (float)x.y);
                }
        o = pkh(m0, m1);
    }
    out[((size_t)n * 512 + s) * 16 + cp] = o;
}

// cat1 = [up2(h_all) 10ci, x1 20ci, pad2] ch-last stride 32 @16^3
__global__ __launch_bounds__(256) void catk(
    const unsigned* __restrict__ h_allu, const unsigned* __restrict__ x1u,
    unsigned* __restrict__ cat1u, int total)
{
    int t = blockIdx.x * 256 + threadIdx.x;
    if (t >= total) return;
    int cp = t & 15, ww = (t >> 4) & 15, hh = (t >> 8) & 15, dd = (t >> 12) & 15, n = t >> 16;
    unsigned v = 0u;
    if (cp < 5) {
        int sph = (dd >> 1) * 64 + (hh >> 1) * 8 + (ww >> 1);
        v = h_allu[((size_t)n * 512 + sph) * 8 + cp];
    } else if (cp < 15) {
        v = x1u[((((size_t)n * 16 + dd) * 16 + hh) * 16 + ww) * 16 + (cp - 5)];
    }
    cat1u[t] = v;
}

// ============================================================================
// treeleafM: per leaf node, MFMA W_iou conv + fused LSTM apply (r11).
// ============================================================================
__global__ __launch_bounds__(256) void treeleafM(
    const _Float16* __restrict__ xp2, const _Float16* __restrict__ bwio,
    const float* __restrict__ b_iou, const float* __restrict__ c0,
    _Float16* __restrict__ h_all, _Float16* __restrict__ c_all)
{
    __shared__ __align__(16) _Float16 buf[16384];
    __shared__ __align__(16) _Float16 bw[13824];
    const int tid = threadIdx.x, lane = tid & 63, wv = tid >> 6;
    const int l16 = lane & 15, quad = lane >> 4;
    const int node = 15 + blockIdx.x;
    const _Float16* xb = xp2 + (size_t)node * 512 * 32;
    const int brot = ((quad + (l16 >> 2)) & 3) << 2;

    int base[8];
#pragma unroll
    for (int i = 0; i < 8; ++i) {
        int s = (wv * 8 + i) * 16 + l16;
        base[i] = ((s >> 6) * 10 + ((s >> 3) & 7)) * 10 + (s & 7);
    }

    f32x4 acc[2][8];
#pragma unroll
    for (int sl = 0; sl < 2; ++sl)
#pragma unroll
        for (int i = 0; i < 8; ++i) acc[sl][i] = f32x4{0.f, 0.f, 0.f, 0.f};

    for (int ck = 0; ck < 2; ++ck) {
        if (ck) __syncthreads();
        {
            const uint4* s0 = (const uint4*)(bwio + (size_t)(0 * 2 + ck) * 6912);
            const uint4* s1 = (const uint4*)(bwio + (size_t)(1 * 2 + ck) * 6912);
#pragma unroll
            for (int it = 0; it < 4; ++it) {
                int t = tid + it * 256;
                if (t < 864) { ((uint4*)bw)[t] = s0[t]; ((uint4*)(bw + 6912))[t] = s1[t]; }
            }
        }
#pragma unroll
        for (int it = 0; it < 8; ++it) {
            int t = tid + it * 256;
            if (t < 2000) {
                int g = t & 1, c = t >> 1;
                int zw = c % 10, r = c / 10, zh = r % 10, zd = r / 10;
                int d = zd - 1, h = zh - 1, w = zw - 1;
                uint4 v = uint4{0u, 0u, 0u, 0u};
                if ((unsigned)d < 8u && (unsigned)h < 8u && (unsigned)w < 8u)
                    v = *(const uint4*)(xb + ((d * 8 + h) * 8 + w) * 32 + ck * 16 + g * 8);
                int rot = (c >> 2) & 3;
                *(uint2*)&buf[c * 16 + (((2 * g + rot) & 3) << 2)]     = make_uint2(v.x, v.y);
                *(uint2*)&buf[c * 16 + (((2 * g + 1 + rot) & 3) << 2)] = make_uint2(v.z, v.w);
            }
        }
        __syncthreads();

        for (int kd = 0; kd < 3; ++kd)
        for (int kh = 0; kh < 3; ++kh)
#pragma unroll
        for (int kw = 0; kw < 3; ++kw) {
            int tap = (kd * 3 + kh) * 3 + kw, toff = kd * 100 + kh * 10 + kw;
            half4_t bf0 = *(const half4_t*)&bw[tap * 256 + l16 * 16 + brot];
            half4_t bf1 = *(const half4_t*)&bw[6912 + tap * 256 + l16 * 16 + brot];
#pragma unroll
            for (int i = 0; i < 8; ++i) {
                int cell = base[i] + toff;
                int arot = ((quad + ((cell >> 2) & 3)) & 3) << 2;
                half4_t af = *(const half4_t*)&buf[cell * 16 + arot];
                acc[0][i] = __builtin_amdgcn_mfma_f32_16x16x16f16(af, bf0, acc[0][i], 0, 0, 0);
                acc[1][i] = __builtin_amdgcn_mfma_f32_16x16x16f16(af, bf1, acc[1][i], 0, 0, 0);
            }
        }
    }
    __syncthreads();
#pragma unroll
    for (int sl = 0; sl < 2; ++sl)
#pragma unroll
        for (int i = 0; i < 8; ++i)
#pragma unroll
            for (int r = 0; r < 4; ++r) {
                int s = (wv * 8 + i) * 16 + quad * 4 + r;
                buf[s * 32 + sl * 16 + l16] = (_Float16)acc[sl][i][r];
            }
    __syncthreads();
    for (int sl2 = 0; sl2 < 2; ++sl2) {
        int s = tid + sl2 * 256;
        const uint4* ip = (const uint4*)&buf[s * 32];
        uint4 q0 = ip[0], q1 = ip[1], q2 = ip[2], q3 = ip[3];
        unsigned uw[16] = {q0.x, q0.y, q0.z, q0.w, q1.x, q1.y, q1.z, q1.w,
                           q2.x, q2.y, q2.z, q2.w, q3.x, q3.y, q3.z, q3.w};
        float io[32];
#pragma unroll
        for (int k = 0; k < 16; ++k) { h2 p = uph(uw[k]); io[2 * k] = (float)p.x; io[2 * k + 1] = (float)p.y; }
        unsigned hp[8], cp[8];
#pragma unroll
        for (int q = 0; q < 5; ++q) {
            float hn[2], cn[2];
#pragma unroll
            for (int e = 0; e < 2; ++e) {
                int chn = 2 * q + e;
                float iv = io[chn]      + b_iou[(size_t)chn * 512 + s];
                float ov = io[10 + chn] + b_iou[(size_t)(10 + chn) * 512 + s];
                float uv = io[20 + chn] + b_iou[(size_t)(20 + chn) * 512 + s];
                float cin = c0[((size_t)node * 10 + chn) * 512 + s];
                cn[e] = sigf(iv) * tanhf(uv) + cin;
                hn[e] = sigf(ov) * tanhf(cn[e]);
            }
            hp[q] = pkh(hn[0], hn[1]);
            cp[q] = pkh(cn[0], cn[1]);
        }
        hp[5] = hp[6] = hp[7] = 0u; cp[5] = cp[6] = cp[7] = 0u;
        uint4* ho = (uint4*)(h_all + ((size_t)node * 512 + s) * 16);
        uint4* co_ = (uint4*)(c_all + ((size_t)node * 512 + s) * 16);
        ho[0] = make_uint4(hp[0], hp[1], hp[2], hp[3]);
        ho[1] = make_uint4(hp[4], hp[5], hp[6], hp[7]);
        co_[0] = make_uint4(cp[0], cp[1], cp[2], cp[3]);
        co_[1] = make_uint4(cp[4], cp[5], cp[6], cp[7]);
    }
}

// ============================================================================
// treelevelM: per parent node; MFMA u_f conv per child + reduce, u_iou conv,
// fused LSTM apply (r11).
// ============================================================================
__global__ __launch_bounds__(256) void treelevelM(
    const _Float16* __restrict__ bwuf, const _Float16* __restrict__ bwui,
    const float* __restrict__ b_iou,
    _Float16* __restrict__ h_all, _Float16* __restrict__ c_all,
    int pb, int cb)
{
    __shared__ __align__(16) _Float16 buf[16384];
    __shared__ __align__(16) _Float16 bw[13824];
    const int tid = threadIdx.x, lane = tid & 63, wv = tid >> 6;
    const int l16 = lane & 15, quad = lane >> 4;
    const int node = pb + blockIdx.x;
    const int c0n = cb + 2 * blockIdx.x;
    const int brot = ((quad + (l16 >> 2)) & 3) << 2;

    int base[8];
#pragma unroll
    for (int i = 0; i < 8; ++i) {
        int s = (wv * 8 + i) * 16 + l16;
        base[i] = ((s >> 6) * 10 + ((s >> 3) & 7)) * 10 + (s & 7);
    }

    float cred[10][2];
#pragma unroll
    for (int c = 0; c < 10; ++c) cred[c][0] = cred[c][1] = 0.f;

#pragma unroll
    for (int it = 0; it < 4; ++it) {
        int t = tid + it * 256;
        if (t < 864) ((uint4*)bw)[t] = ((const uint4*)bwuf)[t];
    }

    for (int e = 0; e < 2; ++e) {
        const _Float16* hb = h_all + (size_t)(c0n + e) * 512 * 16;
        if (e) __syncthreads();
#pragma unroll
        for (int it = 0; it < 8; ++it) {
            int t = tid + it * 256;
            if (t < 2000) {
                int g = t & 1, c = t >> 1;
                int zw = c % 10, r = c / 10, zh = r % 10, zd = r / 10;
                int d = zd - 1, h = zh - 1, w = zw - 1;
                uint4 v = uint4{0u, 0u, 0u, 0u};
                if ((unsigned)d < 8u && (unsigned)h < 8u && (unsigned)w < 8u)
                    v = *(const uint4*)(hb + ((d * 8 + h) * 8 + w) * 16 + g * 8);
                int rot = (c >> 2) & 3;
                *(uint2*)&buf[c * 16 + (((2 * g + rot) & 3) << 2)]     = make_uint2(v.x, v.y);
                *(uint2*)&buf[c * 16 + (((2 * g + 1 + rot) & 3) << 2)] = make_uint2(v.z, v.w);
            }
        }
        __syncthreads();
        f32x4 accf[8];
#pragma unroll
        for (int i = 0; i < 8; ++i) accf[i] = f32x4{0.f, 0.f, 0.f, 0.f};
        for (int kd = 0; kd < 3; ++kd)
        for (int kh = 0; kh < 3; ++kh)
#pragma unroll
        for (int kw = 0; kw < 3; ++kw) {
            int tap = (kd * 3 + kh) * 3 + kw, toff = kd * 100 + kh * 10 + kw;
            half4_t bf = *(const half4_t*)&bw[tap * 256 + l16 * 16 + brot];
#pragma unroll
            for (int i = 0; i < 8; ++i) {
                int cell = base[i] + toff;
                int arot = ((quad + ((cell >> 2) & 3)) & 3) << 2;
                half4_t af = *(const half4_t*)&buf[cell * 16 + arot];
                accf[i] = __builtin_amdgcn_mfma_f32_16x16x16f16(af, bf, accf[i], 0, 0, 0);
            }
        }
        __syncthreads();
#pragma unroll
        for (int i = 0; i < 8; ++i)
#pragma unroll
            for (int r = 0; r < 4; ++r) {
                int s = (wv * 8 + i) * 16 + quad * 4 + r;
                buf[s * 16 + l16] = (_Float16)accf[i][r];
            }
        __syncthreads();
        for (int sl2 = 0; sl2 < 2; ++sl2) {
            int s = tid + sl2 * 256;
            const uint4* fp_ = (const uint4*)&buf[s * 16];
            uint4 f0 = fp_[0], f1 = fp_[1];
            unsigned fw[8] = {f0.x, f0.y, f0.z, f0.w, f1.x, f1.y, f1.z, f1.w};
            const uint4* cc = (const uint4*)(c_all + ((size_t)(c0n + e) * 512 + s) * 16);
            uint4 c0v = cc[0], c1v = cc[1];
            unsigned cw[8] = {c0v.x, c0v.y, c0v.z, c0v.w, c1v.x, c1v.y, c1v.z, c1v.w};
#pragma unroll
            for (int q = 0; q < 5; ++q) {
                h2 fv = uph(fw[q]); h2 cv = uph(cw[q]);
                cred[2 * q][sl2]     += sigf((float)fv.x) * (float)cv.x;
                cred[2 * q + 1][sl2] += sigf((float)fv.y) * (float)cv.y;
            }
        }
    }
    __syncthreads();
#pragma unroll
    for (int it = 0; it < 7; ++it) {
        int t = tid + it * 256;
        if (t < 1728) ((uint4*)bw)[t] = ((const uint4*)bwui)[t];
    }
    {
        const _Float16* h0b = h_all + (size_t)c0n * 512 * 16;
        const _Float16* h1b = h_all + (size_t)(c0n + 1) * 512 * 16;
#pragma unroll
        for (int it = 0; it < 8; ++it) {
            int t = tid + it * 256;
            if (t < 2000) {
                int g = t & 1, c = t >> 1;
                int zw = c % 10, r = c / 10, zh = r % 10, zd = r / 10;
                int d = zd - 1, h = zh - 1, w = zw - 1;
                uint4 v = uint4{0u, 0u, 0u, 0u};
                if ((unsigned)d < 8u && (unsigned)h < 8u && (unsigned)w < 8u) {
                    size_t off = ((d * 8 + h) * 8 + w) * 16 + g * 8;
                    uint4 a = *(const uint4*)(h0b + off);
                    uint4 b = *(const uint4*)(h1b + off);
                    unsigned* av = &a.x; unsigned* bv = &b.x; unsigned* vv = &v.x;
#pragma unroll
                    for (int k = 0; k < 4; ++k) {
                        h2 x = uph(av[k]); h2 y = uph(bv[k]);
                        vv[k] = pkh((float)x.x + (float)y.x, (float)x.y + (float)y.y);
                    }
                }
                int rot = (c >> 2) & 3;
                *(uint2*)&buf[c * 16 + (((2 * g + rot) & 3) << 2)]     = make_uint2(v.x, v.y);
                *(uint2*)&buf[c * 16 + (((2 * g + 1 + rot) & 3) << 2)] = make_uint2(v.z, v.w);
            }
        }
    }
    __syncthreads();
    f32x4 acc[2][8];
#pragma unroll
    for (int sl = 0; sl < 2; ++sl)
#pragma unroll
        for (int i = 0; i < 8; ++i) acc[sl][i] = f32x4{0.f, 0.f, 0.f, 0.f};
    for (int kd = 0; kd < 3; ++kd)
    for (int kh = 0; kh < 3; ++kh)
#pragma unroll
    for (int kw = 0; kw < 3; ++kw) {
        int tap = (kd * 3 + kh) * 3 + kw, toff = kd * 100 + kh * 10 + kw;
        half4_t bf0 = *(const half4_t*)&bw[tap * 256 + l16 * 16 + brot];
        half4_t bf1 = *(const half4_t*)&bw[6912 + tap * 256 + l16 * 16 + brot];
#pragma unroll
        for (int i = 0; i < 8; ++i) {
            int cell = base[i] + toff;
            int arot = ((quad + ((cell >> 2) & 3)) & 3) << 2;
            half4_t af = *(const half4_t*)&buf[cell * 16 + arot];
            acc[0][i] = __builtin_amdgcn_mfma_f32_16x16x16f16(af, bf0, acc[0][i], 0, 0, 0);
            acc[1][i] = __builtin_amdgcn_mfma_f32_16x16x16f16(af, bf1, acc[1][i], 0, 0, 0);
        }
    }
    __syncthreads();
#pragma unroll
    for (int sl = 0; sl < 2; ++sl)
#pragma unroll
        for (int i = 0; i < 8; ++i)
#pragma unroll
            for (int r = 0; r < 4; ++r) {
                int s = (wv * 8 + i) * 16 + quad * 4 + r;
                buf[s * 32 + sl * 16 + l16] = (_Float16)acc[sl][i][r];
            }
    __syncthreads();
    for (int sl2 = 0; sl2 < 2; ++sl2) {
        int s = tid + sl2 * 256;
        const uint4* ip = (const uint4*)&buf[s * 32];
        uint4 q0 = ip[0], q1 = ip[1], q2 = ip[2], q3 = ip[3];
        unsigned uw[16] = {q0.x, q0.y, q0.z, q0.w, q1.x, q1.y, q1.z, q1.w,
                           q2.x, q2.y, q2.z, q2.w, q3.x, q3.y, q3.z, q3.w};
        float io[32];
#pragma unroll
        for (int k = 0; k < 16; ++k) { h2 p = uph(uw[k]); io[2 * k] = (float)p.x; io[2 * k + 1] = (float)p.y; }
        unsigned hp[8], cp[8];
#pragma unroll
        for (int q = 0; q < 5; ++q) {
            float hn[2], cn[2];
#pragma unroll
            for (int e = 0; e < 2; ++e) {
                int chn = 2 * q + e;
                float iv = io[chn]      + b_iou[(size_t)chn * 512 + s];
                float ov = io[10 + chn] + b_iou[(size_t)(10 + chn) * 512 + s];
                float uv = io[20 + chn] + b_iou[(size_t)(20 + chn) * 512 + s];
                cn[e] = sigf(iv) * tanhf(uv) + cred[chn][sl2];
                hn[e] = sigf(ov) * tanhf(cn[e]);
            }
            hp[q] = pkh(hn[0], hn[1]);
            cp[q] = pkh(cn[0], cn[1]);
        }
        hp[5] = hp[6] = hp[7] = 0u; cp[5] = cp[6] = cp[7] = 0u;
        uint4* ho = (uint4*)(h_all + ((size_t)node * 512 + s) * 16);
        uint4* co_ = (uint4*)(c_all + ((size_t)node * 512 + s) * 16);
        ho[0] = make_uint4(hp[0], hp[1], hp[2], hp[3]);
        ho[1] = make_uint4(hp[4], hp[5], hp[6], hp[7]);
        co_[0] = make_uint4(cp[0], cp[1], cp[2], cp[3]);
        co_[1] = make_uint4(cp[4], cp[5], cp[6], cp[7]);
    }
}

extern "C" void kernel_launch(void* const* d_in, const int* in_sizes, int n_in,
                              void* d_out, int out_size, void* d_ws, size_t ws_size,
                              hipStream_t stream)
{
    const float* data  = (const float*)d_in[0];
    const float* c0    = (const float*)d_in[2];
    const float* e1a_w = (const float*)d_in[3];  const float* e1a_b = (const float*)d_in[4];
    const float* e1b_w = (const float*)d_in[5];  const float* e1b_b = (const float*)d_in[6];
    const float* e2a_w = (const float*)d_in[7];  const float* e2a_b = (const float*)d_in[8];
    const float* e2b_w = (const float*)d_in[9];  const float* e2b_b = (const float*)d_in[10];
    const float* d2a_w = (const float*)d_in[11]; const float* d2a_b = (const float*)d_in[12];
    const float* d2b_w = (const float*)d_in[13]; const float* d2b_b = (const float*)d_in[14];
    const float* d1a_w = (const float*)d_in[15]; const float* d1a_b = (const float*)d_in[16];
    const float* d1b_w = (const float*)d_in[17]; const float* d1b_b = (const float*)d_in[18];
    const float* d1c_w = (const float*)d_in[19]; const float* d1c_b = (const float*)d_in[20];
    const float* w_iou = (const float*)d_in[21];
    const float* u_iou = (const float*)d_in[22];
    const float* u_f   = (const float*)d_in[23];
    const float* b_iou = (const float*)d_in[24];

    unsigned* ws = (unsigned*)d_ws;
    size_t o = 0;
    unsigned* t1u   = ws + o; o += 8126464;   // t1 [31,32^3,16] ch-last (reused as t4)
    unsigned* x0u   = ws + o; o += 8126464;   // x0 [31,32^3,16]
    unsigned* xpu   = ws + o; o += 1015808;   // xp [31,16^3,16]
    unsigned* t2u   = ws + o; o += 2031616;   // t2 [31,16^3,32] (reused as t3)
    unsigned* x1u   = ws + o; o += 2031616;   // x1 [31,16^3,32] (20 real)
    unsigned* cat1u = ws + o; o += 2031616;   // cat1 [31,16^3,32] (30 real)
    unsigned* y2u   = ws + o; o += 2031616;   // y2 [31,16^3,32]
    unsigned* xp2u  = ws + o; o += 253952;    // xp2 ch-last [31,512,32] (20 real)
    unsigned* h_allu= ws + o; o += 126976;    // h ch-last [31,512,16] (10 real)
    unsigned* c_allu= ws + o; o += 126976;
    unsigned* bwgu  = ws + o; o += 89856;     // 179712 f16 pre-packed weights
    (void)ws_size; (void)in_sizes; (void)n_in; (void)out_size;

    _Float16* t1h  = (_Float16*)t1u;
    _Float16* x0h  = (_Float16*)x0u;
    _Float16* xph  = (_Float16*)xpu;
    _Float16* t2h  = (_Float16*)t2u;
    _Float16* x1h  = (_Float16*)x1u;
    _Float16* cath = (_Float16*)cat1u;
    _Float16* y2h  = (_Float16*)y2u;
    _Float16* xp2h = (_Float16*)xp2u;
    _Float16* h_allh = (_Float16*)h_allu;
    _Float16* c_allh = (_Float16*)c_allu;
    _Float16* t3h  = t2h;
    _Float16* t4h  = t1h;
    _Float16* bwg  = (_Float16*)bwgu;

    _Float16* b_e1b = bwg;            // 6912
    _Float16* b_e2a = bwg + 6912;     // 13824
    _Float16* b_e2b = bwg + 20736;    // 27648
    _Float16* b_d2a = bwg + 48384;    // 27648
    _Float16* b_d2b = bwg + 76032;    // 27648
    _Float16* b_d1a = bwg + 103680;   // 20736
    _Float16* b_d1b = bwg + 124416;   // 6912
    _Float16* b_wio = bwg + 131328;   // 27648
    _Float16* b_uio = bwg + 158976;   // 13824
    _Float16* b_uf  = bwg + 172800;   // 6912

    dim3 b256(256);

    // ---- one-shot weight repack ----
    repackall<<<dim3(702), b256, 0, stream>>>(
        e1b_w, e2a_w, e2b_w, d2a_w, d2b_w, d1a_w, d1b_w, w_iou, u_iou, u_f, bwg);

    // ---- Encoder ----
    conv3e1a<<<dim3(992), b256, 0, stream>>>(data, e1a_w, e1a_b, t1h);
    conv3m32<1, 0, 0, 16, false><<<dim3(1984), b256, 0, stream>>>(
        nullptr, t1h, b_e1b, e1b_b, x0h, nullptr, nullptr, nullptr);
    maxpool16<<<dim3(3968), b256, 0, stream>>>(x0u, xpu, 1015808);
    conv3m16<1, 2, 16, 32><<<dim3(496), b256, 0, stream>>>(xph, b_e2a, e2a_b, t2h);
    conv3m16<2, 2, 32, 20><<<dim3(496), b256, 0, stream>>>(t2h, b_e2b, e2b_b, x1h);
    poolx1<<<dim3(992), b256, 0, stream>>>(x1u, xp2u, 253952);

    // ---- Tree (MFMA) ----
    treeleafM<<<dim3(16), b256, 0, stream>>>(xp2h, b_wio, b_iou, c0, h_allh, c_allh);
    for (int lvl = 3; lvl >= 0; --lvl) {
        int P = 1 << lvl;
        treelevelM<<<dim3(P), b256, 0, stream>>>(
            b_uf, b_uio, b_iou, h_allh, c_allh, P - 1, 2 * P - 1);
    }

    // ---- Decoder ----
    catk<<<dim3(7936), b256, 0, stream>>>(h_allu, x1u, cat1u, 2031616);
    conv3m16<2, 2, 32, 20><<<dim3(496), b256, 0, stream>>>(cath, b_d2a, d2a_b, t3h);
    conv3m16<2, 2, 32, 32><<<dim3(496), b256, 0, stream>>>(t3h, b_d2b, d2b_b, y2h);
    conv3m32<3, 32, 32, 16, false><<<dim3(1984), b256, 0, stream>>>(
        y2h, x0h, b_d1a, d1a_b, t4h, nullptr, nullptr, nullptr);
    conv3m32<1, 0, 0, 16, true><<<dim3(1984), b256, 0, stream>>>(
        nullptr, t4h, b_d1b, d1b_b, nullptr, d1c_w, d1c_b, (float*)d_out);
}

// Round 13
// 525.013 us; speedup vs baseline: 1.0590x; 1.0590x over previous
//
#include <hip/hip_runtime.h>
#include <math.h>

typedef _Float16 h2 __attribute__((ext_vector_type(2)));
typedef _Float16 half4_t __attribute__((ext_vector_type(4)));
typedef float f32x4 __attribute__((ext_vector_type(4)));

__device__ inline h2 uph(unsigned u) { return __builtin_bit_cast(h2, u); }
__device__ inline unsigned pkh(float a, float b) {
    return __builtin_bit_cast(unsigned, __builtin_amdgcn_cvt_pkrtz(a, b));
}
__device__ inline float sigf(float x) { return 1.f / (1.f + expf(-x)); }

// ============================================================================
// repackall: all 10 weight tensors -> f16 [slab][chunk][tap][co16][ci16-rot]
// in one launch. ci slot (ci>>2) rotated by (co>>2)&3 (LDS bank floor).
// ============================================================================
__global__ __launch_bounds__(256) void repackall(
    const float* __restrict__ s0, const float* __restrict__ s1,
    const float* __restrict__ s2, const float* __restrict__ s3,
    const float* __restrict__ s4, const float* __restrict__ s5,
    const float* __restrict__ s6, const float* __restrict__ s7,
    const float* __restrict__ s8, const float* __restrict__ s9,
    _Float16* __restrict__ dst)
{
    int t = blockIdx.x * 256 + threadIdx.x;
    if (t >= 179712) return;
    const int offs[11] = {0, 6912, 20736, 48384, 76032, 103680, 124416,
                          131328, 158976, 172800, 179712};
    const int ciwA[10] = {16, 16, 32, 30, 20, 48, 16, 20, 10, 10};
    const int coA[10]  = {16, 32, 20, 20, 32, 16, 16, 30, 30, 10};
    const int nchA[10] = {1, 1, 2, 2, 2, 3, 1, 2, 1, 1};
    int seg = 0;
    while (t >= offs[seg + 1]) ++seg;
    int lt = t - offs[seg];
    const float* src = seg == 0 ? s0 : seg == 1 ? s1 : seg == 2 ? s2 :
                       seg == 3 ? s3 : seg == 4 ? s4 : seg == 5 ? s5 :
                       seg == 6 ? s6 : seg == 7 ? s7 : seg == 8 ? s8 : s9;
    int CIw = ciwA[seg], CO = coA[seg], NCH = nchA[seg];
    int cip = lt & 15, co = (lt >> 4) & 15, r = lt >> 8;
    int tap = r % 27, rc = r / 27;
    int chunk = rc % NCH, slab = rc / NCH;
    int slot_l = ((cip >> 2) - (co >> 2)) & 3;
    int gci = chunk * 16 + slot_l * 4 + (cip & 3);
    int gco = slab * 16 + co;
    float v = 0.f;
    if (gci < CIw && gco < CO) v = src[((size_t)gco * CIw + gci) * 27 + tap];
    dst[t] = (_Float16)v;
}

// ============================================================================
// conv3m: D=32 MFMA implicit-GEMM 3x3x3 conv, M=256 (8-row band), CO=16.
// r11 version: 46.6KB LDS, swizzled A/B, cross-chunk register prefetch.
// FUSE: d1c 1x1x1 conv folded into epilogue via 16-lane shfl_xor reduce.
// ============================================================================
template<int NCH, int UPP, int UP2, int S2, bool FUSE>
__global__ __launch_bounds__(256) void conv3m(
    const _Float16* __restrict__ up, const _Float16* __restrict__ src,
    const _Float16* __restrict__ bwg, const float* __restrict__ bias,
    _Float16* __restrict__ out, const float* __restrict__ w1c,
    const float* __restrict__ b1c, float* __restrict__ out32)
{
    constexpr int ROWS = 10, COLS = 34;
    constexpr int NG   = 3 * ROWS * COLS * 2;   // 2040 16B granules
    constexpr int ITERS = 8;

    __shared__ __align__(16) _Float16 win[3 * ROWS * COLS * 16];
    __shared__ __align__(16) _Float16 bw[6912];

    const int tid  = threadIdx.x;
    const int lane = tid & 63;
    const int wv   = tid >> 6;
    const int l16  = lane & 15;
    const int quad = lane >> 4;

    const int h0 = (blockIdx.x & 3) * 8;
    const int d  = (blockIdx.x >> 2) & 31;
    const int n  = blockIdx.x >> 7;

    size_t baseU[ITERS], baseS[ITERS];
    int dA[ITERS], dB[ITERS];
    bool vld[ITERS];
#pragma unroll
    for (int it = 0; it < ITERS; ++it) {
        int t = tid + it * 256;
        vld[it] = false; dA[it] = 0; dB[it] = 0; baseU[it] = 0; baseS[it] = 0;
        if (t < NG) {
            int g   = t & 1;
            int idx = t >> 1;
            int cc  = idx % COLS;
            int rr  = idx / COLS;
            int hh  = rr % ROWS;
            int dp  = rr / ROWS;
            int zd = d - 1 + dp, zh = h0 + hh - 1, zw = cc - 1;
            vld[it] = (unsigned)zd < 32u && (unsigned)zh < 32u && (unsigned)zw < 32u;
            int rot  = (cc >> 2) & 3;
            int cell = (rr * COLS + cc) * 16;
            dA[it] = cell + (((2 * g + rot) & 3) << 2);
            dB[it] = cell + (((2 * g + 1 + rot) & 3) << 2);
            if (vld[it]) {
                if (UPP > 0)
                    baseU[it] = ((((size_t)n * 16 + (zd >> 1)) * 16 + (zh >> 1)) * 16
                                 + (zw >> 1)) * UP2 + g * 8;
                baseS[it] = ((((size_t)n * 32 + zd) * 32 + zh) * 32 + zw) * S2 + g * 8;
            }
        }
    }

    f32x4 acc[4];
    {
        float b0 = bias[l16];
#pragma unroll
        for (int i = 0; i < 4; ++i) acc[i] = f32x4{b0, b0, b0, b0};
    }

    const int brot = ((quad + (l16 >> 2)) & 3) << 2;

    uint4 preA[ITERS];
    uint4 preB[4];

    auto loadA = [&](int cib) {
        const int cb = cib * 16;
        const bool isup = (UPP > 0) && (cb < UPP);
#pragma unroll
        for (int it = 0; it < ITERS; ++it) {
            int t = tid + it * 256;
            uint4 v = uint4{0u, 0u, 0u, 0u};
            if (t < NG && vld[it]) {
                const _Float16* pp = isup ? (up + baseU[it] + cb)
                                          : (src + baseS[it] + (cb - UPP));
                v = *(const uint4*)pp;
            }
            preA[it] = v;
        }
    };
    auto loadB = [&](int cib) {
        const uint4* bsrc = (const uint4*)(bwg + (size_t)cib * 6912);
#pragma unroll
        for (int it = 0; it < 4; ++it) {
            int t = tid + it * 256;
            preB[it] = (t < 864) ? bsrc[t] : uint4{0u, 0u, 0u, 0u};
        }
    };

    loadA(0);
    loadB(0);

#pragma unroll
    for (int cib = 0; cib < NCH; ++cib) {
        if (cib) __syncthreads();
#pragma unroll
        for (int it = 0; it < 4; ++it) {
            int t = tid + it * 256;
            if (t < 864) ((uint4*)bw)[t] = preB[it];
        }
#pragma unroll
        for (int it = 0; it < ITERS; ++it) {
            int t = tid + it * 256;
            if (t < NG) {
                *(uint2*)&win[dA[it]] = make_uint2(preA[it].x, preA[it].y);
                *(uint2*)&win[dB[it]] = make_uint2(preA[it].z, preA[it].w);
            }
        }
        if (cib + 1 < NCH) { loadA(cib + 1); loadB(cib + 1); }
        __syncthreads();

#pragma unroll
        for (int kd = 0; kd < 3; ++kd) {
#pragma unroll
            for (int kw = 0; kw < 3; ++kw) {
                half4_t bf[3];
#pragma unroll
                for (int kh = 0; kh < 3; ++kh)
                    bf[kh] = *(const half4_t*)&bw[((kd * 3 + kh) * 3 + kw) * 256 + l16 * 16 + brot];
                half4_t af[2][4];
#pragma unroll
                for (int p = 0; p < 2; ++p) {
                    const int ww = p * 16 + l16 + kw;
                    const int arot = ((quad + (ww >> 2)) & 3) << 2;
#pragma unroll
                    for (int rr = 0; rr < 4; ++rr) {
                        const int row = kd * ROWS + wv * 2 + rr;
                        af[p][rr] = *(const half4_t*)&win[(row * COLS + ww) * 16 + arot];
                    }
                }
#pragma unroll
                for (int kh = 0; kh < 3; ++kh)
#pragma unroll
                    for (int i = 0; i < 4; ++i)
                        acc[i] = __builtin_amdgcn_mfma_f32_16x16x16f16(
                            af[i & 1][(i >> 1) + kh], bf[kh], acc[i], 0, 0, 0);
            }
        }
    }

    // epilogue: C layout col=l16=co, row=quad*4+r
    if (FUSE) {
        const float wc = w1c[l16];
        const float bb = b1c[0];
#pragma unroll
        for (int i = 0; i < 4; ++i) {
            const int h = h0 + wv * 2 + (i >> 1);
            const int wb0 = (i & 1) * 16;
#pragma unroll
            for (int r = 0; r < 4; ++r) {
                float v = fmaxf(acc[i][r], 0.f) * wc;
                v += __shfl_xor(v, 1);
                v += __shfl_xor(v, 2);
                v += __shfl_xor(v, 4);
                v += __shfl_xor(v, 8);
                if (l16 == 0) {
                    const int w = wb0 + quad * 4 + r;
                    out32[(((size_t)n * 32 + d) * 32 + h) * 32 + w] = v + bb;
                }
            }
        }
    } else {
#pragma unroll
        for (int i = 0; i < 4; ++i) {
            const int h = h0 + wv * 2 + (i >> 1);
            const int wb0 = (i & 1) * 16;
#pragma unroll
            for (int r = 0; r < 4; ++r) {
                const int w = wb0 + quad * 4 + r;
                size_t sp = (((size_t)n * 32 + d) * 32 + h) * 32 + w;
                out[sp * 16 + l16] = (_Float16)fmaxf(acc[i][r], 0.f);
            }
        }
    }
}

// ============================================================================
// conv3m16: D=16 MFMA conv, M=256 (full plane), NSLAB co-slabs per block.
// A-fragments shared across slabs (r12 — verified).
// ============================================================================
template<int NCH, int NSLAB, int S2, int CO>
__global__ __launch_bounds__(256) void conv3m16(
    const _Float16* __restrict__ src, const _Float16* __restrict__ bwg,
    const float* __restrict__ bias, _Float16* __restrict__ out)
{
    constexpr int ROWS = 18, COLS = 18;
    constexpr int CELLS = 3 * ROWS * COLS;   // 972
    constexpr int ITERS = 4;

    __shared__ __align__(16) _Float16 win[CELLS * 16];
    __shared__ __align__(16) _Float16 bw[NSLAB * 6912];

    const int tid  = threadIdx.x;
    const int lane = tid & 63;
    const int wv   = tid >> 6;
    const int l16  = lane & 15;
    const int quad = lane >> 4;

    const int d = blockIdx.x & 15;
    const int n = blockIdx.x >> 4;

    unsigned baseS[ITERS], pk[ITERS];
    bool vld[ITERS];
#pragma unroll
    for (int it = 0; it < ITERS; ++it) {
        int t = tid + it * 256;
        vld[it] = false; baseS[it] = 0; pk[it] = 0;
        if (t < CELLS) {
            int cc = t % COLS, rr = t / COLS;
            int hh = rr % ROWS, dp = rr / ROWS;
            int zd = d - 1 + dp, zh = hh - 1, zw = cc - 1;
            vld[it] = (unsigned)zd < 16u && (unsigned)zh < 16u && (unsigned)zw < 16u;
            pk[it] = (unsigned)(t * 16) | ((unsigned)((cc >> 2) & 3) << 28);
            if (vld[it])
                baseS[it] = (unsigned)((((n * 16 + zd) * 16 + zh) * 16 + zw) * S2);
        }
    }

    f32x4 acc[NSLAB][4];
#pragma unroll
    for (int s = 0; s < NSLAB; ++s) {
        int cg = s * 16 + l16;
        float b0 = (cg < CO) ? bias[cg] : 0.f;
#pragma unroll
        for (int i = 0; i < 4; ++i) acc[s][i] = f32x4{b0, b0, b0, b0};
    }
    const int brot = ((quad + (l16 >> 2)) & 3) << 2;

    uint4 preA0[ITERS], preA1[ITERS], preB[NSLAB][4];

    auto loadA = [&](int cib) {
        const int cb = cib * 16;
#pragma unroll
        for (int it = 0; it < ITERS; ++it) {
            uint4 v0 = uint4{0u, 0u, 0u, 0u}, v1 = v0;
            int t = tid + it * 256;
            if (t < CELLS && vld[it]) {
                const _Float16* p = src + baseS[it] + cb;
                v0 = *(const uint4*)p;
                v1 = *(const uint4*)(p + 8);
            }
            preA0[it] = v0; preA1[it] = v1;
        }
    };
    auto loadB = [&](int cib) {
#pragma unroll
        for (int s = 0; s < NSLAB; ++s) {
            const uint4* bsrc = (const uint4*)(bwg + (size_t)(s * NCH + cib) * 6912);
#pragma unroll
            for (int it = 0; it < 4; ++it) {
                int t = tid + it * 256;
                preB[s][it] = (t < 864) ? bsrc[t] : uint4{0u, 0u, 0u, 0u};
            }
        }
    };

    loadA(0);
    loadB(0);

#pragma unroll
    for (int cib = 0; cib < NCH; ++cib) {
        if (cib) __syncthreads();
#pragma unroll
        for (int s = 0; s < NSLAB; ++s)
#pragma unroll
            for (int it = 0; it < 4; ++it) {
                int t = tid + it * 256;
                if (t < 864) ((uint4*)(bw + s * 6912))[t] = preB[s][it];
            }
#pragma unroll
        for (int it = 0; it < ITERS; ++it) {
            int t = tid + it * 256;
            if (t < CELLS) {
                int cell = pk[it] & 0x0FFFFFFF;
                int rot  = pk[it] >> 28;
                *(uint2*)&win[cell + (((rot + 0) & 3) << 2)] = make_uint2(preA0[it].x, preA0[it].y);
                *(uint2*)&win[cell + (((rot + 1) & 3) << 2)] = make_uint2(preA0[it].z, preA0[it].w);
                *(uint2*)&win[cell + (((rot + 2) & 3) << 2)] = make_uint2(preA1[it].x, preA1[it].y);
                *(uint2*)&win[cell + (((rot + 3) & 3) << 2)] = make_uint2(preA1[it].z, preA1[it].w);
            }
        }
        if (cib + 1 < NCH) { loadA(cib + 1); loadB(cib + 1); }
        __syncthreads();

#pragma unroll
        for (int kd = 0; kd < 3; ++kd) {
#pragma unroll
            for (int kw = 0; kw < 3; ++kw) {
                half4_t af[6];
                const int ww = l16 + kw;
                const int arot = ((quad + (ww >> 2)) & 3) << 2;
#pragma unroll
                for (int rr = 0; rr < 6; ++rr) {
                    const int row = kd * ROWS + wv * 4 + rr;
                    af[rr] = *(const half4_t*)&win[(row * COLS + ww) * 16 + arot];
                }
#pragma unroll
                for (int kh = 0; kh < 3; ++kh) {
                    const int tap = (kd * 3 + kh) * 3 + kw;
#pragma unroll
                    for (int s = 0; s < NSLAB; ++s) {
                        half4_t bf = *(const half4_t*)&bw[s * 6912 + tap * 256 + l16 * 16 + brot];
#pragma unroll
                        for (int i = 0; i < 4; ++i)
                            acc[s][i] = __builtin_amdgcn_mfma_f32_16x16x16f16(
                                af[i + kh], bf, acc[s][i], 0, 0, 0);
                    }
                }
            }
        }
    }

#pragma unroll
    for (int s = 0; s < NSLAB; ++s) {
        int cg = s * 16 + l16;
        if (cg < CO) {
#pragma unroll
            for (int i = 0; i < 4; ++i) {
                const int h = wv * 4 + i;
#pragma unroll
                for (int r = 0; r < 4; ++r) {
                    const int w = quad * 4 + r;
                    size_t sp = (((size_t)n * 16 + d) * 16 + h) * 16 + w;
                    out[sp * 32 + cg] = (_Float16)fmaxf(acc[s][i][r], 0.f);
                }
            }
        }
    }
}

// e1a: 1 fp32 input channel -> 16 co, D=32, channels-last out (stride 16)
__global__ __launch_bounds__(256) void conv3e1a(
    const float* __restrict__ src, const float* __restrict__ wgt,
    const float* __restrict__ bias, _Float16* __restrict__ out)
{
    __shared__ float sw[27 * 16];
    const int tid = threadIdx.x;
    const int wq = tid % 8;
    const int h  = (tid / 8) % 32;
    const int w0 = wq * 4;
    const int n  = blockIdx.x / 32;
    const int d  = blockIdx.x % 32;

    for (int t = tid; t < 27 * 16; t += 256) {
        int co = t % 16, tap = t / 16;
        sw[t] = wgt[(size_t)co * 27 + tap];
    }
    __syncthreads();

    float acc[16][4];
#pragma unroll
    for (int co = 0; co < 16; ++co) {
        float b0 = bias[co];
        acc[co][0] = b0; acc[co][1] = b0; acc[co][2] = b0; acc[co][3] = b0;
    }

#pragma unroll
    for (int kd = 0; kd < 3; ++kd) {
        int zd = d + kd - 1;
        if ((unsigned)zd >= 32u) continue;
#pragma unroll
        for (int kh = 0; kh < 3; ++kh) {
            int zh = h + kh - 1;
            if ((unsigned)zh >= 32u) continue;
            const float* p = src + ((size_t)n * 32 + zd) * 1024 + zh * 32;
            float v[6];
#pragma unroll
            for (int j = 0; j < 6; ++j) {
                int zw = w0 - 1 + j;
                v[j] = ((unsigned)zw < 32u) ? p[zw] : 0.f;
            }
            const float* swp = &sw[(kd * 9 + kh * 3) * 16];
#pragma unroll
            for (int kw = 0; kw < 3; ++kw)
#pragma unroll
                for (int co = 0; co < 16; ++co)
#pragma unroll
                    for (int j = 0; j < 4; ++j)
                        acc[co][j] = fmaf(v[kw + j], swp[kw * 16 + co], acc[co][j]);
        }
    }

#pragma unroll
    for (int j = 0; j < 4; ++j) {
        unsigned u[8];
#pragma unroll
        for (int cp = 0; cp < 8; ++cp)
            u[cp] = pkh(fmaxf(acc[2 * cp][j], 0.f), fmaxf(acc[2 * cp + 1][j], 0.f));
        _Float16* base = out + ((((size_t)n * 32 + d) * 32 + h) * 32 + (w0 + j)) * 16;
        *(uint4*)base       = make_uint4(u[0], u[1], u[2], u[3]);
        *(uint4*)(base + 8) = make_uint4(u[4], u[5], u[6], u[7]);
    }
}

// 2x2x2 maxpool, channels-last stride-16 (x0 32^3 -> xp 16^3)
__global__ __launch_bounds__(256) void maxpool16(
    const unsigned* __restrict__ in, unsigned* __restrict__ out, int total)
{
    int t = blockIdx.x * 256 + threadIdx.x;
    if (t >= total) return;
    int cp = t & 7, w = (t >> 3) & 15, h = (t >> 7) & 15, d = (t >> 11) & 15, n = t >> 15;
    float m0 = -1e30f, m1 = -1e30f;
#pragma unroll
    for (int a = 0; a < 2; ++a)
#pragma unroll
        for (int b = 0; b < 2; ++b)
#pragma unroll
            for (int c = 0; c < 2; ++c) {
                size_t sp = (((size_t)n * 32 + 2 * d + a) * 32 + 2 * h + b) * 32 + 2 * w + c;
                h2 x = uph(in[sp * 8 + cp]);
                m0 = fmaxf(m0, (float)x.x);
                m1 = fmaxf(m1, (float)x.y);
            }
    out[(((size_t)(n * 16 + d) * 16 + h) * 16 + w) * 8 + cp] = pkh(m0, m1);
}

// 2x2x2 maxpool: x1 (ch-last stride 32 @16^3) -> xp2 ch-last [31][512][32]
__global__ __launch_bounds__(256) void poolx1(
    const unsigned* __restrict__ x1u, unsigned* __restrict__ out, int total)
{
    int t = blockIdx.x * 256 + threadIdx.x;
    if (t >= total) return;
    int cp = t & 15, s = (t >> 4) & 511, n = t >> 13;
    int w = s & 7, h = (s >> 3) & 7, d = s >> 6;
    unsigned o = 0u;
    if (cp < 10) {
        float m0 = -1e30f, m1 = -1e30f;
#pragma unroll
        for (int a = 0; a < 2; ++a)
#pragma unroll
            for (int b = 0; b < 2; ++b)
#pragma unroll
                for (int c = 0; c < 2; ++c) {
                    size_t sp = (((size_t)n * 16 + 2 * d + a) * 16 + 2 * h + b) * 16 + 2 * w + c;
                    h2 x = uph(x1u[sp * 16 + cp]);
                    m0 = fmaxf(m0, (float)x.x);
                    m1 = fmaxf(m1, (float)x.y);
                }
        o = pkh(m0, m1);
    }
    out[((size_t)n * 512 + s) * 16 + cp] = o;
}

// cat1 = [up2(h_all) 10ci, x1 20ci, pad2] ch-last stride 32 @16^3
__global__ __launch_bounds__(256) void catk(
    const unsigned* __restrict__ h_allu, const unsigned* __restrict__ x1u,
    unsigned* __restrict__ cat1u, int total)
{
    int t = blockIdx.x * 256 + threadIdx.x;
    if (t >= total) return;
    int cp = t & 15, ww = (t >> 4) & 15, hh = (t >> 8) & 15, dd = (t >> 12) & 15, n = t >> 16;
    unsigned v = 0u;
    if (cp < 5) {
        int sph = (dd >> 1) * 64 + (hh >> 1) * 8 + (ww >> 1);
        v = h_allu[((size_t)n * 512 + sph) * 8 + cp];
    } else if (cp < 15) {
        v = x1u[((((size_t)n * 16 + dd) * 16 + hh) * 16 + ww) * 16 + (cp - 5)];
    }
    cat1u[t] = v;
}

// ============================================================================
// treeleafM: per leaf node, MFMA W_iou conv + fused LSTM apply (r11).
// ============================================================================
__global__ __launch_bounds__(256) void treeleafM(
    const _Float16* __restrict__ xp2, const _Float16* __restrict__ bwio,
    const float* __restrict__ b_iou, const float* __restrict__ c0,
    _Float16* __restrict__ h_all, _Float16* __restrict__ c_all)
{
    __shared__ __align__(16) _Float16 buf[16384];
    __shared__ __align__(16) _Float16 bw[13824];
    const int tid = threadIdx.x, lane = tid & 63, wv = tid >> 6;
    const int l16 = lane & 15, quad = lane >> 4;
    const int node = 15 + blockIdx.x;
    const _Float16* xb = xp2 + (size_t)node * 512 * 32;
    const int brot = ((quad + (l16 >> 2)) & 3) << 2;

    int base[8];
#pragma unroll
    for (int i = 0; i < 8; ++i) {
        int s = (wv * 8 + i) * 16 + l16;
        base[i] = ((s >> 6) * 10 + ((s >> 3) & 7)) * 10 + (s & 7);
    }

    f32x4 acc[2][8];
#pragma unroll
    for (int sl = 0; sl < 2; ++sl)
#pragma unroll
        for (int i = 0; i < 8; ++i) acc[sl][i] = f32x4{0.f, 0.f, 0.f, 0.f};

    for (int ck = 0; ck < 2; ++ck) {
        if (ck) __syncthreads();
        {
            const uint4* s0 = (const uint4*)(bwio + (size_t)(0 * 2 + ck) * 6912);
            const uint4* s1 = (const uint4*)(bwio + (size_t)(1 * 2 + ck) * 6912);
#pragma unroll
            for (int it = 0; it < 4; ++it) {
                int t = tid + it * 256;
                if (t < 864) { ((uint4*)bw)[t] = s0[t]; ((uint4*)(bw + 6912))[t] = s1[t]; }
            }
        }
#pragma unroll
        for (int it = 0; it < 8; ++it) {
            int t = tid + it * 256;
            if (t < 2000) {
                int g = t & 1, c = t >> 1;
                int zw = c % 10, r = c / 10, zh = r % 10, zd = r / 10;
                int d = zd - 1, h = zh - 1, w = zw - 1;
                uint4 v = uint4{0u, 0u, 0u, 0u};
                if ((unsigned)d < 8u && (unsigned)h < 8u && (unsigned)w < 8u)
                    v = *(const uint4*)(xb + ((d * 8 + h) * 8 + w) * 32 + ck * 16 + g * 8);
                int rot = (c >> 2) & 3;
                *(uint2*)&buf[c * 16 + (((2 * g + rot) & 3) << 2)]     = make_uint2(v.x, v.y);
                *(uint2*)&buf[c * 16 + (((2 * g + 1 + rot) & 3) << 2)] = make_uint2(v.z, v.w);
            }
        }
        __syncthreads();

        for (int kd = 0; kd < 3; ++kd)
        for (int kh = 0; kh < 3; ++kh)
#pragma unroll
        for (int kw = 0; kw < 3; ++kw) {
            int tap = (kd * 3 + kh) * 3 + kw, toff = kd * 100 + kh * 10 + kw;
            half4_t bf0 = *(const half4_t*)&bw[tap * 256 + l16 * 16 + brot];
            half4_t bf1 = *(const half4_t*)&bw[6912 + tap * 256 + l16 * 16 + brot];
#pragma unroll
            for (int i = 0; i < 8; ++i) {
                int cell = base[i] + toff;
                int arot = ((quad + ((cell >> 2) & 3)) & 3) << 2;
                half4_t af = *(const half4_t*)&buf[cell * 16 + arot];
                acc[0][i] = __builtin_amdgcn_mfma_f32_16x16x16f16(af, bf0, acc[0][i], 0, 0, 0);
                acc[1][i] = __builtin_amdgcn_mfma_f32_16x16x16f16(af, bf1, acc[1][i], 0, 0, 0);
            }
        }
    }
    __syncthreads();
#pragma unroll
    for (int sl = 0; sl < 2; ++sl)
#pragma unroll
        for (int i = 0; i < 8; ++i)
#pragma unroll
            for (int r = 0; r < 4; ++r) {
                int s = (wv * 8 + i) * 16 + quad * 4 + r;
                buf[s * 32 + sl * 16 + l16] = (_Float16)acc[sl][i][r];
            }
    __syncthreads();
    for (int sl2 = 0; sl2 < 2; ++sl2) {
        int s = tid + sl2 * 256;
        const uint4* ip = (const uint4*)&buf[s * 32];
        uint4 q0 = ip[0], q1 = ip[1], q2 = ip[2], q3 = ip[3];
        unsigned uw[16] = {q0.x, q0.y, q0.z, q0.w, q1.x, q1.y, q1.z, q1.w,
                           q2.x, q2.y, q2.z, q2.w, q3.x, q3.y, q3.z, q3.w};
        float io[32];
#pragma unroll
        for (int k = 0; k < 16; ++k) { h2 p = uph(uw[k]); io[2 * k] = (float)p.x; io[2 * k + 1] = (float)p.y; }
        unsigned hp[8], cp[8];
#pragma unroll
        for (int q = 0; q < 5; ++q) {
            float hn[2], cn[2];
#pragma unroll
            for (int e = 0; e < 2; ++e) {
                int chn = 2 * q + e;
                float iv = io[chn]      + b_iou[(size_t)chn * 512 + s];
                float ov = io[10 + chn] + b_iou[(size_t)(10 + chn) * 512 + s];
                float uv = io[20 + chn] + b_iou[(size_t)(20 + chn) * 512 + s];
                float cin = c0[((size_t)node * 10 + chn) * 512 + s];
                cn[e] = sigf(iv) * tanhf(uv) + cin;
                hn[e] = sigf(ov) * tanhf(cn[e]);
            }
            hp[q] = pkh(hn[0], hn[1]);
            cp[q] = pkh(cn[0], cn[1]);
        }
        hp[5] = hp[6] = hp[7] = 0u; cp[5] = cp[6] = cp[7] = 0u;
        uint4* ho = (uint4*)(h_all + ((size_t)node * 512 + s) * 16);
        uint4* co_ = (uint4*)(c_all + ((size_t)node * 512 + s) * 16);
        ho[0] = make_uint4(hp[0], hp[1], hp[2], hp[3]);
        ho[1] = make_uint4(hp[4], hp[5], hp[6], hp[7]);
        co_[0] = make_uint4(cp[0], cp[1], cp[2], cp[3]);
        co_[1] = make_uint4(cp[4], cp[5], cp[6], cp[7]);
    }
}

// ============================================================================
// treelevelM: per parent node; MFMA u_f conv per child + reduce, u_iou conv,
// fused LSTM apply (r11).
// ============================================================================
__global__ __launch_bounds__(256) void treelevelM(
    const _Float16* __restrict__ bwuf, const _Float16* __restrict__ bwui,
    const float* __restrict__ b_iou,
    _Float16* __restrict__ h_all, _Float16* __restrict__ c_all,
    int pb, int cb)
{
    __shared__ __align__(16) _Float16 buf[16384];
    __shared__ __align__(16) _Float16 bw[13824];
    const int tid = threadIdx.x, lane = tid & 63, wv = tid >> 6;
    const int l16 = lane & 15, quad = lane >> 4;
    const int node = pb + blockIdx.x;
    const int c0n = cb + 2 * blockIdx.x;
    const int brot = ((quad + (l16 >> 2)) & 3) << 2;

    int base[8];
#pragma unroll
    for (int i = 0; i < 8; ++i) {
        int s = (wv * 8 + i) * 16 + l16;
        base[i] = ((s >> 6) * 10 + ((s >> 3) & 7)) * 10 + (s & 7);
    }

    float cred[10][2];
#pragma unroll
    for (int c = 0; c < 10; ++c) cred[c][0] = cred[c][1] = 0.f;

#pragma unroll
    for (int it = 0; it < 4; ++it) {
        int t = tid + it * 256;
        if (t < 864) ((uint4*)bw)[t] = ((const uint4*)bwuf)[t];
    }

    for (int e = 0; e < 2; ++e) {
        const _Float16* hb = h_all + (size_t)(c0n + e) * 512 * 16;
        if (e) __syncthreads();
#pragma unroll
        for (int it = 0; it < 8; ++it) {
            int t = tid + it * 256;
            if (t < 2000) {
                int g = t & 1, c = t >> 1;
                int zw = c % 10, r = c / 10, zh = r % 10, zd = r / 10;
                int d = zd - 1, h = zh - 1, w = zw - 1;
                uint4 v = uint4{0u, 0u, 0u, 0u};
                if ((unsigned)d < 8u && (unsigned)h < 8u && (unsigned)w < 8u)
                    v = *(const uint4*)(hb + ((d * 8 + h) * 8 + w) * 16 + g * 8);
                int rot = (c >> 2) & 3;
                *(uint2*)&buf[c * 16 + (((2 * g + rot) & 3) << 2)]     = make_uint2(v.x, v.y);
                *(uint2*)&buf[c * 16 + (((2 * g + 1 + rot) & 3) << 2)] = make_uint2(v.z, v.w);
            }
        }
        __syncthreads();
        f32x4 accf[8];
#pragma unroll
        for (int i = 0; i < 8; ++i) accf[i] = f32x4{0.f, 0.f, 0.f, 0.f};
        for (int kd = 0; kd < 3; ++kd)
        for (int kh = 0; kh < 3; ++kh)
#pragma unroll
        for (int kw = 0; kw < 3; ++kw) {
            int tap = (kd * 3 + kh) * 3 + kw, toff = kd * 100 + kh * 10 + kw;
            half4_t bf = *(const half4_t*)&bw[tap * 256 + l16 * 16 + brot];
#pragma unroll
            for (int i = 0; i < 8; ++i) {
                int cell = base[i] + toff;
                int arot = ((quad + ((cell >> 2) & 3)) & 3) << 2;
                half4_t af = *(const half4_t*)&buf[cell * 16 + arot];
                accf[i] = __builtin_amdgcn_mfma_f32_16x16x16f16(af, bf, accf[i], 0, 0, 0);
            }
        }
        __syncthreads();
#pragma unroll
        for (int i = 0; i < 8; ++i)
#pragma unroll
            for (int r = 0; r < 4; ++r) {
                int s = (wv * 8 + i) * 16 + quad * 4 + r;
                buf[s * 16 + l16] = (_Float16)accf[i][r];
            }
        __syncthreads();
        for (int sl2 = 0; sl2 < 2; ++sl2) {
            int s = tid + sl2 * 256;
            const uint4* fp_ = (const uint4*)&buf[s * 16];
            uint4 f0 = fp_[0], f1 = fp_[1];
            unsigned fw[8] = {f0.x, f0.y, f0.z, f0.w, f1.x, f1.y, f1.z, f1.w};
            const uint4* cc = (const uint4*)(c_all + ((size_t)(c0n + e) * 512 + s) * 16);
            uint4 c0v = cc[0], c1v = cc[1];
            unsigned cw[8] = {c0v.x, c0v.y, c0v.z, c0v.w, c1v.x, c1v.y, c1v.z, c1v.w};
#pragma unroll
            for (int q = 0; q < 5; ++q) {
                h2 fv = uph(fw[q]); h2 cv = uph(cw[q]);
                cred[2 * q][sl2]     += sigf((float)fv.x) * (float)cv.x;
                cred[2 * q + 1][sl2] += sigf((float)fv.y) * (float)cv.y;
            }
        }
    }
    __syncthreads();
#pragma unroll
    for (int it = 0; it < 7; ++it) {
        int t = tid + it * 256;
        if (t < 1728) ((uint4*)bw)[t] = ((const uint4*)bwui)[t];
    }
    {
        const _Float16* h0b = h_all + (size_t)c0n * 512 * 16;
        const _Float16* h1b = h_all + (size_t)(c0n + 1) * 512 * 16;
#pragma unroll
        for (int it = 0; it < 8; ++it) {
            int t = tid + it * 256;
            if (t < 2000) {
                int g = t & 1, c = t >> 1;
                int zw = c % 10, r = c / 10, zh = r % 10, zd = r / 10;
                int d = zd - 1, h = zh - 1, w = zw - 1;
                uint4 v = uint4{0u, 0u, 0u, 0u};
                if ((unsigned)d < 8u && (unsigned)h < 8u && (unsigned)w < 8u) {
                    size_t off = ((d * 8 + h) * 8 + w) * 16 + g * 8;
                    uint4 a = *(const uint4*)(h0b + off);
                    uint4 b = *(const uint4*)(h1b + off);
                    unsigned* av = &a.x; unsigned* bv = &b.x; unsigned* vv = &v.x;
#pragma unroll
                    for (int k = 0; k < 4; ++k) {
                        h2 x = uph(av[k]); h2 y = uph(bv[k]);
                        vv[k] = pkh((float)x.x + (float)y.x, (float)x.y + (float)y.y);
                    }
                }
                int rot = (c >> 2) & 3;
                *(uint2*)&buf[c * 16 + (((2 * g + rot) & 3) << 2)]     = make_uint2(v.x, v.y);
                *(uint2*)&buf[c * 16 + (((2 * g + 1 + rot) & 3) << 2)] = make_uint2(v.z, v.w);
            }
        }
    }
    __syncthreads();
    f32x4 acc[2][8];
#pragma unroll
    for (int sl = 0; sl < 2; ++sl)
#pragma unroll
        for (int i = 0; i < 8; ++i) acc[sl][i] = f32x4{0.f, 0.f, 0.f, 0.f};
    for (int kd = 0; kd < 3; ++kd)
    for (int kh = 0; kh < 3; ++kh)
#pragma unroll
    for (int kw = 0; kw < 3; ++kw) {
        int tap = (kd * 3 + kh) * 3 + kw, toff = kd * 100 + kh * 10 + kw;
        half4_t bf0 = *(const half4_t*)&bw[tap * 256 + l16 * 16 + brot];
        half4_t bf1 = *(const half4_t*)&bw[6912 + tap * 256 + l16 * 16 + brot];
#pragma unroll
        for (int i = 0; i < 8; ++i) {
            int cell = base[i] + toff;
            int arot = ((quad + ((cell >> 2) & 3)) & 3) << 2;
            half4_t af = *(const half4_t*)&buf[cell * 16 + arot];
            acc[0][i] = __builtin_amdgcn_mfma_f32_16x16x16f16(af, bf0, acc[0][i], 0, 0, 0);
            acc[1][i] = __builtin_amdgcn_mfma_f32_16x16x16f16(af, bf1, acc[1][i], 0, 0, 0);
        }
    }
    __syncthreads();
#pragma unroll
    for (int sl = 0; sl < 2; ++sl)
#pragma unroll
        for (int i = 0; i < 8; ++i)
#pragma unroll
            for (int r = 0; r < 4; ++r) {
                int s = (wv * 8 + i) * 16 + quad * 4 + r;
                buf[s * 32 + sl * 16 + l16] = (_Float16)acc[sl][i][r];
            }
    __syncthreads();
    for (int sl2 = 0; sl2 < 2; ++sl2) {
        int s = tid + sl2 * 256;
        const uint4* ip = (const uint4*)&buf[s * 32];
        uint4 q0 = ip[0], q1 = ip[1], q2 = ip[2], q3 = ip[3];
        unsigned uw[16] = {q0.x, q0.y, q0.z, q0.w, q1.x, q1.y, q1.z, q1.w,
                           q2.x, q2.y, q2.z, q2.w, q3.x, q3.y, q3.z, q3.w};
        float io[32];
#pragma unroll
        for (int k = 0; k < 16; ++k) { h2 p = uph(uw[k]); io[2 * k] = (float)p.x; io[2 * k + 1] = (float)p.y; }
        unsigned hp[8], cp[8];
#pragma unroll
        for (int q = 0; q < 5; ++q) {
            float hn[2], cn[2];
#pragma unroll
            for (int e = 0; e < 2; ++e) {
                int chn = 2 * q + e;
                float iv = io[chn]      + b_iou[(size_t)chn * 512 + s];
                float ov = io[10 + chn] + b_iou[(size_t)(10 + chn) * 512 + s];
                float uv = io[20 + chn] + b_iou[(size_t)(20 + chn) * 512 + s];
                cn[e] = sigf(iv) * tanhf(uv) + cred[chn][sl2];
                hn[e] = sigf(ov) * tanhf(cn[e]);
            }
            hp[q] = pkh(hn[0], hn[1]);
            cp[q] = pkh(cn[0], cn[1]);
        }
        hp[5] = hp[6] = hp[7] = 0u; cp[5] = cp[6] = cp[7] = 0u;
        uint4* ho = (uint4*)(h_all + ((size_t)node * 512 + s) * 16);
        uint4* co_ = (uint4*)(c_all + ((size_t)node * 512 + s) * 16);
        ho[0] = make_uint4(hp[0], hp[1], hp[2], hp[3]);
        ho[1] = make_uint4(hp[4], hp[5], hp[6], hp[7]);
        co_[0] = make_uint4(cp[0], cp[1], cp[2], cp[3]);
        co_[1] = make_uint4(cp[4], cp[5], cp[6], cp[7]);
    }
}

extern "C" void kernel_launch(void* const* d_in, const int* in_sizes, int n_in,
                              void* d_out, int out_size, void* d_ws, size_t ws_size,
                              hipStream_t stream)
{
    const float* data  = (const float*)d_in[0];
    const float* c0    = (const float*)d_in[2];
    const float* e1a_w = (const float*)d_in[3];  const float* e1a_b = (const float*)d_in[4];
    const float* e1b_w = (const float*)d_in[5];  const float* e1b_b = (const float*)d_in[6];
    const float* e2a_w = (const float*)d_in[7];  const float* e2a_b = (const float*)d_in[8];
    const float* e2b_w = (const float*)d_in[9];  const float* e2b_b = (const float*)d_in[10];
    const float* d2a_w = (const float*)d_in[11]; const float* d2a_b = (const float*)d_in[12];
    const float* d2b_w = (const float*)d_in[13]; const float* d2b_b = (const float*)d_in[14];
    const float* d1a_w = (const float*)d_in[15]; const float* d1a_b = (const float*)d_in[16];
    const float* d1b_w = (const float*)d_in[17]; const float* d1b_b = (const float*)d_in[18];
    const float* d1c_w = (const float*)d_in[19]; const float* d1c_b = (const float*)d_in[20];
    const float* w_iou = (const float*)d_in[21];
    const float* u_iou = (const float*)d_in[22];
    const float* u_f   = (const float*)d_in[23];
    const float* b_iou = (const float*)d_in[24];

    unsigned* ws = (unsigned*)d_ws;
    size_t o = 0;
    unsigned* t1u   = ws + o; o += 8126464;   // t1 [31,32^3,16] ch-last (reused as t4)
    unsigned* x0u   = ws + o; o += 8126464;   // x0 [31,32^3,16]
    unsigned* xpu   = ws + o; o += 1015808;   // xp [31,16^3,16]
    unsigned* t2u   = ws + o; o += 2031616;   // t2 [31,16^3,32] (reused as t3)
    unsigned* x1u   = ws + o; o += 2031616;   // x1 [31,16^3,32] (20 real)
    unsigned* cat1u = ws + o; o += 2031616;   // cat1 [31,16^3,32] (30 real)
    unsigned* y2u   = ws + o; o += 2031616;   // y2 [31,16^3,32]
    unsigned* xp2u  = ws + o; o += 253952;    // xp2 ch-last [31,512,32] (20 real)
    unsigned* h_allu= ws + o; o += 126976;    // h ch-last [31,512,16] (10 real)
    unsigned* c_allu= ws + o; o += 126976;
    unsigned* bwgu  = ws + o; o += 89856;     // 179712 f16 pre-packed weights
    (void)ws_size; (void)in_sizes; (void)n_in; (void)out_size;

    _Float16* t1h  = (_Float16*)t1u;
    _Float16* x0h  = (_Float16*)x0u;
    _Float16* xph  = (_Float16*)xpu;
    _Float16* t2h  = (_Float16*)t2u;
    _Float16* x1h  = (_Float16*)x1u;
    _Float16* cath = (_Float16*)cat1u;
    _Float16* y2h  = (_Float16*)y2u;
    _Float16* xp2h = (_Float16*)xp2u;
    _Float16* h_allh = (_Float16*)h_allu;
    _Float16* c_allh = (_Float16*)c_allu;
    _Float16* t3h  = t2h;
    _Float16* t4h  = t1h;
    _Float16* bwg  = (_Float16*)bwgu;

    _Float16* b_e1b = bwg;            // 6912
    _Float16* b_e2a = bwg + 6912;     // 13824
    _Float16* b_e2b = bwg + 20736;    // 27648
    _Float16* b_d2a = bwg + 48384;    // 27648
    _Float16* b_d2b = bwg + 76032;    // 27648
    _Float16* b_d1a = bwg + 103680;   // 20736
    _Float16* b_d1b = bwg + 124416;   // 6912
    _Float16* b_wio = bwg + 131328;   // 27648
    _Float16* b_uio = bwg + 158976;   // 13824
    _Float16* b_uf  = bwg + 172800;   // 6912

    dim3 b256(256);

    // ---- one-shot weight repack ----
    repackall<<<dim3(702), b256, 0, stream>>>(
        e1b_w, e2a_w, e2b_w, d2a_w, d2b_w, d1a_w, d1b_w, w_iou, u_iou, u_f, bwg);

    // ---- Encoder ----
    conv3e1a<<<dim3(992), b256, 0, stream>>>(data, e1a_w, e1a_b, t1h);
    conv3m<1, 0, 0, 16, false><<<dim3(3968), b256, 0, stream>>>(
        nullptr, t1h, b_e1b, e1b_b, x0h, nullptr, nullptr, nullptr);
    maxpool16<<<dim3(3968), b256, 0, stream>>>(x0u, xpu, 1015808);
    conv3m16<1, 2, 16, 32><<<dim3(496), b256, 0, stream>>>(xph, b_e2a, e2a_b, t2h);
    conv3m16<2, 2, 32, 20><<<dim3(496), b256, 0, stream>>>(t2h, b_e2b, e2b_b, x1h);
    poolx1<<<dim3(992), b256, 0, stream>>>(x1u, xp2u, 253952);

    // ---- Tree (MFMA) ----
    treeleafM<<<dim3(16), b256, 0, stream>>>(xp2h, b_wio, b_iou, c0, h_allh, c_allh);
    for (int lvl = 3; lvl >= 0; --lvl) {
        int P = 1 << lvl;
        treelevelM<<<dim3(P), b256, 0, stream>>>(
            b_uf, b_uio, b_iou, h_allh, c_allh, P - 1, 2 * P - 1);
    }

    // ---- Decoder ----
    catk<<<dim3(7936), b256, 0, stream>>>(h_allu, x1u, cat1u, 2031616);
    conv3m16<2, 2, 32, 20><<<dim3(496), b256, 0, stream>>>(cath, b_d2a, d2a_b, t3h);
    conv3m16<2, 2, 32, 32><<<dim3(496), b256, 0, stream>>>(t3h, b_d2b, d2b_b, y2h);
    conv3m<3, 32, 32, 16, false><<<dim3(3968), b256, 0, stream>>>(
        y2h, x0h, b_d1a, d1a_b, t4h, nullptr, nullptr, nullptr);
    conv3m<1, 0, 0, 16, true><<<dim3(3968), b256, 0, stream>>>(
        nullptr, t4h, b_d1b, d1b_b, nullptr, d1c_w, d1c_b, (float*)d_out);
}